// Round 5
// baseline (178.572 us; speedup 1.0000x reference)
//
#include <hip/hip_runtime.h>

typedef unsigned short u16;
typedef unsigned int   u32;
typedef __bf16 bf16x8 __attribute__((ext_vector_type(8)));
typedef float  f32x4  __attribute__((ext_vector_type(4)));

// Geometry (fixed): b=32, h=w=56, C=192, NH=6, hd=32, WS=7, shift=3
// 2048 windows, 49 tokens (padded to 64). One block (4 waves) per window.
// V5: 5 barriers/block, barrier-free 6-head attention, q/O in registers,
//     biasM precomputed. LDS 66 KB -> 2 blocks/CU, VGPR budget 256.

__device__ __forceinline__ u16 f2b(float f){
  return __builtin_bit_cast(u16, (__bf16)f);
}
__device__ __forceinline__ u32 pk2(float a, float b){
  return (u32)f2b(a) | ((u32)f2b(b) << 16);
}

__device__ __forceinline__ int coords_fn(int t){ return (t/7)*13 + (t%7); }
__device__ __forceinline__ int code_fn(int t, int wy, int wx){
  const int ty = t/7, tx = t%7;
  const int hp = wy*7 + ty, wp = wx*7 + tx;
  const int rh = (hp < 49) ? 0 : ((hp < 53) ? 1 : 2);
  const int rw = (wp < 49) ? 0 : ((wp < 53) ? 1 : 2);
  return rh*3 + rw;
}

// prep: weights fp32->bf16, plus biasM[h][i][j] = rpb bias with j-invalid mask folded
__global__ __launch_bounds__(256) void prep_kernel(const float* __restrict__ qkvw,
                                                   const float* __restrict__ projw,
                                                   const float* __restrict__ rpb,
                                                   u16* __restrict__ wq, u16* __restrict__ wp,
                                                   float* __restrict__ biasM){
  const int i = blockIdx.x * 256 + threadIdx.x;
  if (i < 576*192) wq[i] = f2b(qkvw[i]);
  if (i < 192*192) wp[i] = f2b(projw[i]);
  if (i < 6*64*72){
    const int h = i / 4608, rem = i % 4608, ii = rem / 72, j = rem % 72;
    float v = -1e30f;
    if (j < 49){
      const int icl = (ii > 48) ? 48 : ii;
      v = rpb[(coords_fn(icl) + coords_fn(48 - j))*6 + h];
    }
    biasM[i] = v;
  }
}

__global__ __launch_bounds__(256, 2) void fused_kernel(const float* __restrict__ x,
    const u16* __restrict__ wq, const float* __restrict__ qb,
    const u16* __restrict__ wp, const float* __restrict__ pb,
    const float* __restrict__ biasM, float* __restrict__ out)
{
  __shared__ u16 KX[64][200];    // X tile -> k natural [tok][ch] -> AO [tok][ch]
  __shared__ u16 vTsh[192][72];  // v^T [ch][tok]
  __shared__ u16 Psh[4][16][72]; // per-wave P [i-local][j]
  __shared__ u16 qst[4][16][40]; // per-wave per-head q slice [i-local][d]

  const int wi = blockIdx.x;
  const int bb = wi >> 6, wy = (wi >> 3) & 7, wx = wi & 7;
  const int tid = threadIdx.x;
  const int wave = tid >> 6, lane = tid & 63;
  const int g = lane >> 4, r = lane & 15;
  const f32x4 z4 = {0.f, 0.f, 0.f, 0.f};

  // ---- phase 1: roll + window gather, fp32 -> bf16, rows >=49 zeroed ----
  for (int it = tid; it < 64*48; it += 256){
    const int row = it / 48, c4 = (it % 48) * 4;
    u32 p0 = 0, p1 = 0;
    if (row < 49){
      const int ty = row / 7, tx = row % 7;
      int sh = wy*7 + ty + 3; if (sh >= 56) sh -= 56;
      int sw = wx*7 + tx + 3; if (sw >= 56) sw -= 56;
      const float4 f = *reinterpret_cast<const float4*>(x + (size_t)(((bb*56 + sh)*56 + sw))*192 + c4);
      p0 = pk2(f.x, f.y);
      p1 = pk2(f.z, f.w);
    }
    u32* dst = reinterpret_cast<u32*>(&KX[row][c4]);
    dst[0] = p0; dst[1] = p1;
  }
  __syncthreads();   // B1: X ready

  // ---- phase 2a: q (swapped MFMA) -> packed registers ----
  // wave w owns toks 16w..16w+15; lane (g,r): tok = 16w+r, chs 16*cht+4g+reg
  u32 qpk[12][2];
  {
    f32x4 qa[12];
    #pragma unroll
    for (int cht = 0; cht < 12; ++cht) qa[cht] = z4;
    #pragma unroll
    for (int ks = 0; ks < 6; ++ks){
      const bf16x8 bq = *reinterpret_cast<const bf16x8*>(&KX[wave*16 + r][ks*32 + 8*g]);
      #pragma unroll
      for (int cht = 0; cht < 12; ++cht){
        const bf16x8 aw = *reinterpret_cast<const bf16x8*>(wq + (size_t)(cht*16 + r)*192 + ks*32 + 8*g);
        qa[cht] = __builtin_amdgcn_mfma_f32_16x16x32_bf16(aw, bq, qa[cht], 0, 0, 0);
      }
    }
    #pragma unroll
    for (int cht = 0; cht < 12; ++cht){
      const float4 bi = *reinterpret_cast<const float4*>(qb + cht*16 + 4*g);
      const float S = 0.17677669529663687f;
      qpk[cht][0] = pk2((qa[cht][0] + bi.x)*S, (qa[cht][1] + bi.y)*S);
      qpk[cht][1] = pk2((qa[cht][2] + bi.z)*S, (qa[cht][3] + bi.w)*S);
    }
  }

  // ---- phase 2b: v (normal MFMA) -> vTsh[ch][tok] via uint2 ----
  {
    f32x4 va[4][3];
    #pragma unroll
    for (int mt = 0; mt < 4; ++mt)
      #pragma unroll
      for (int nt = 0; nt < 3; ++nt) va[mt][nt] = z4;
    #pragma unroll
    for (int ks = 0; ks < 6; ++ks){
      bf16x8 ax[4];
      #pragma unroll
      for (int mt = 0; mt < 4; ++mt)
        ax[mt] = *reinterpret_cast<const bf16x8*>(&KX[mt*16 + r][ks*32 + 8*g]);
      #pragma unroll
      for (int nt = 0; nt < 3; ++nt){
        const bf16x8 bw = *reinterpret_cast<const bf16x8*>(wq + (size_t)(384 + wave*48 + nt*16 + r)*192 + ks*32 + 8*g);
        #pragma unroll
        for (int mt = 0; mt < 4; ++mt)
          va[mt][nt] = __builtin_amdgcn_mfma_f32_16x16x32_bf16(ax[mt], bw, va[mt][nt], 0, 0, 0);
      }
    }
    #pragma unroll
    for (int nt = 0; nt < 3; ++nt){
      const float bv = qb[384 + wave*48 + nt*16 + r];
      #pragma unroll
      for (int mt = 0; mt < 4; ++mt){
        uint2 t;
        t.x = pk2(va[mt][nt][0] + bv, va[mt][nt][1] + bv);
        t.y = pk2(va[mt][nt][2] + bv, va[mt][nt][3] + bv);
        *reinterpret_cast<uint2*>(&vTsh[wave*48 + nt*16 + r][mt*16 + 4*g]) = t;
      }
    }
  }

  // ---- phase 2c: k (swapped MFMA) -> accumulate, then overwrite KX after B2 ----
  {
    f32x4 ka[3][4];
    #pragma unroll
    for (int c = 0; c < 3; ++c)
      #pragma unroll
      for (int tt = 0; tt < 4; ++tt) ka[c][tt] = z4;
    #pragma unroll
    for (int ks = 0; ks < 6; ++ks){
      bf16x8 aw[3];
      #pragma unroll
      for (int c = 0; c < 3; ++c)
        aw[c] = *reinterpret_cast<const bf16x8*>(wq + (size_t)(192 + wave*48 + c*16 + r)*192 + ks*32 + 8*g);
      #pragma unroll
      for (int tt = 0; tt < 4; ++tt){
        const bf16x8 bx = *reinterpret_cast<const bf16x8*>(&KX[tt*16 + r][ks*32 + 8*g]);
        #pragma unroll
        for (int c = 0; c < 3; ++c)
          ka[c][tt] = __builtin_amdgcn_mfma_f32_16x16x32_bf16(aw[c], bx, ka[c][tt], 0, 0, 0);
      }
    }
    __syncthreads();   // B2: all X reads done; KX now reusable as k
    #pragma unroll
    for (int c = 0; c < 3; ++c){
      const float4 bi = *reinterpret_cast<const float4*>(qb + 192 + wave*48 + c*16 + 4*g);
      #pragma unroll
      for (int tt = 0; tt < 4; ++tt){
        uint2 t;
        t.x = pk2(ka[c][tt][0] + bi.x, ka[c][tt][1] + bi.y);
        t.y = pk2(ka[c][tt][2] + bi.z, ka[c][tt][3] + bi.w);
        *reinterpret_cast<uint2*>(&KX[tt*16 + r][wave*48 + c*16 + 4*g]) = t;
      }
    }
  }
  __syncthreads();   // B3: k + vT ready

  // ---- attention metadata: lane query i = 16*wave + r ----
  const int i_r = wave*16 + r;
  float maskM[4][4];   // +-100 window-boundary mask (j-invalid handled by biasM)
  {
    const int icl = (i_r > 48) ? 48 : i_r;
    const int codei = code_fn(icl, wy, wx);
    #pragma unroll
    for (int mt = 0; mt < 4; ++mt)
      #pragma unroll
      for (int jj = 0; jj < 4; ++jj){
        const int j = 16*mt + 4*g + jj;
        maskM[mt][jj] = (j < 49) ? ((codei == code_fn(j, wy, wx)) ? 0.f : -100.f) : 0.f;
      }
  }
  const float* bM = biasM + (size_t)i_r * 72;

  // ---- phase 3: 6 heads, NO barriers (per-wave qst/Ps; k/vT read-only) ----
  u32 opk[6][2][2];
  #pragma unroll
  for (int h = 0; h < 6; ++h){
    // bias loads (L2) issued first
    float4 bf[4];
    #pragma unroll
    for (int mt = 0; mt < 4; ++mt)
      bf[mt] = *reinterpret_cast<const float4*>(bM + (size_t)h*64*72 + mt*16 + 4*g);
    // stage this head's q slice (own wave, own row)
    uint2 q0; q0.x = qpk[2*h][0];   q0.y = qpk[2*h][1];
    uint2 q1; q1.x = qpk[2*h+1][0]; q1.y = qpk[2*h+1][1];
    *reinterpret_cast<uint2*>(&qst[wave][r][4*g])      = q0;
    *reinterpret_cast<uint2*>(&qst[wave][r][16 + 4*g]) = q1;
    const bf16x8 aq = *reinterpret_cast<const bf16x8*>(&qst[wave][r][8*g]);
    // QK^T swapped: lane holds row i=i_r, 16 in-lane j
    f32x4 s[4];
    #pragma unroll
    for (int mt = 0; mt < 4; ++mt){
      const bf16x8 ak = *reinterpret_cast<const bf16x8*>(&KX[mt*16 + r][h*32 + 8*g]);
      s[mt] = __builtin_amdgcn_mfma_f32_16x16x32_bf16(ak, aq, z4, 0, 0, 0);
    }
    float mx = -1e30f;
    #pragma unroll
    for (int mt = 0; mt < 4; ++mt)
      #pragma unroll
      for (int jj = 0; jj < 4; ++jj){
        const float t = s[mt][jj] + bf[mt][jj] + maskM[mt][jj];
        s[mt][jj] = t;
        mx = fmaxf(mx, t);
      }
    mx = fmaxf(mx, __shfl_xor(mx, 16));
    mx = fmaxf(mx, __shfl_xor(mx, 32));
    float sum = 0.f;
    #pragma unroll
    for (int mt = 0; mt < 4; ++mt)
      #pragma unroll
      for (int jj = 0; jj < 4; ++jj){
        const float p = __expf(s[mt][jj] - mx);
        s[mt][jj] = p;
        sum += p;
      }
    sum += __shfl_xor(sum, 16);
    sum += __shfl_xor(sum, 32);
    const float rs = 1.0f / sum;
    #pragma unroll
    for (int mt = 0; mt < 4; ++mt){
      uint2 pw;
      pw.x = pk2(s[mt][0]*rs, s[mt][1]*rs);
      pw.y = pk2(s[mt][2]*rs, s[mt][3]*rs);
      *reinterpret_cast<uint2*>(&Psh[wave][r][16*mt + 4*g]) = pw;
    }
    // PV swapped: lane -> O[tok=i_r][4 consecutive chs per nt]
    f32x4 o[2] = {z4, z4};
    #pragma unroll
    for (int k2 = 0; k2 < 2; ++k2){
      const bf16x8 bp = *reinterpret_cast<const bf16x8*>(&Psh[wave][r][32*k2 + 8*g]);
      #pragma unroll
      for (int nt = 0; nt < 2; ++nt){
        const bf16x8 av = *reinterpret_cast<const bf16x8*>(&vTsh[h*32 + nt*16 + r][32*k2 + 8*g]);
        o[nt] = __builtin_amdgcn_mfma_f32_16x16x32_bf16(av, bp, o[nt], 0, 0, 0);
      }
    }
    opk[h][0][0] = pk2(o[0][0], o[0][1]); opk[h][0][1] = pk2(o[0][2], o[0][3]);
    opk[h][1][0] = pk2(o[1][0], o[1][1]); opk[h][1][1] = pk2(o[1][2], o[1][3]);
  }

  __syncthreads();   // B4: all attention reads of k/vT done; KX reusable as AO
  #pragma unroll
  for (int h = 0; h < 6; ++h)
    #pragma unroll
    for (int nt = 0; nt < 2; ++nt){
      uint2 t; t.x = opk[h][nt][0]; t.y = opk[h][nt][1];
      *reinterpret_cast<uint2*>(&KX[wave*16 + r][h*32 + nt*16 + 4*g]) = t;
    }
  __syncthreads();   // B5: AO ready

  // ---- phase 4: proj GEMM + window-reverse + roll-back ----
  {
    f32x4 pacc[4][3];
    #pragma unroll
    for (int mt = 0; mt < 4; ++mt){ pacc[mt][0] = z4; pacc[mt][1] = z4; pacc[mt][2] = z4; }
    #pragma unroll
    for (int ks = 0; ks < 6; ++ks){
      bf16x8 a2[4];
      #pragma unroll
      for (int mt = 0; mt < 4; ++mt)
        a2[mt] = *reinterpret_cast<const bf16x8*>(&KX[mt*16 + r][ks*32 + 8*g]);
      #pragma unroll
      for (int nt = 0; nt < 3; ++nt){
        const bf16x8 bw = *reinterpret_cast<const bf16x8*>(wp + (size_t)(wave*48 + nt*16 + r)*192 + ks*32 + 8*g);
        #pragma unroll
        for (int mt = 0; mt < 4; ++mt)
          pacc[mt][nt] = __builtin_amdgcn_mfma_f32_16x16x32_bf16(a2[mt], bw, pacc[mt][nt], 0, 0, 0);
      }
    }
    #pragma unroll
    for (int nt = 0; nt < 3; ++nt){
      const int n = wave*48 + nt*16 + r;
      const float bias = pb[n];
      #pragma unroll
      for (int mt = 0; mt < 4; ++mt)
        #pragma unroll
        for (int jj = 0; jj < 4; ++jj){
          const int tok = mt*16 + 4*g + jj;
          if (tok < 49){
            const int ty = tok/7, tx = tok%7;
            int dh = wy*7 + ty + 3; if (dh >= 56) dh -= 56;
            int dw = wx*7 + tx + 3; if (dw >= 56) dw -= 56;
            out[(size_t)((bb*56 + dh)*56 + dw)*192 + n] = pacc[mt][nt][jj] + bias;
          }
        }
    }
  }
}

extern "C" void kernel_launch(void* const* d_in, const int* in_sizes, int n_in,
                              void* d_out, int out_size, void* d_ws, size_t ws_size,
                              hipStream_t stream) {
  const float* x     = (const float*)d_in[0];
  const float* rpb   = (const float*)d_in[1];
  const float* qkvw  = (const float*)d_in[2];
  const float* qkvb  = (const float*)d_in[3];
  const float* projw = (const float*)d_in[4];
  const float* projb = (const float*)d_in[5];
  float* out = (float*)d_out;

  char* ws = (char*)d_ws;
  u16*   wq    = (u16*)(ws);                      // bf16 [576][192]
  u16*   wpj   = (u16*)(ws + 221184);             // bf16 [192][192]
  float* biasM = (float*)(ws + 221184 + 73728);   // f32  [6][64][72]

  prep_kernel <<<432, 256, 0, stream>>>(qkvw, projw, rpb, wq, wpj, biasM);
  fused_kernel<<<2048, 256, 0, stream>>>(x, wq, qkvb, wpj, projb, biasM, out);
}